// Round 7
// baseline (1154.992 us; speedup 1.0000x reference)
//
#include <hip/hip_runtime.h>

// Problem dims
#define TT 512
#define DXX 128
#define HH 256
#define DZZ 64

typedef __attribute__((ext_vector_type(8))) short short8;
typedef __attribute__((ext_vector_type(4))) float f32x4;

#define DEV static __device__ __forceinline__
#define MFMA(a,b,c) __builtin_amdgcn_mfma_f32_16x16x32_bf16((a),(b),(c),0,0,0)

DEV unsigned short f2bf(float f){
  unsigned u = __builtin_bit_cast(unsigned, f);
  u += 0x7FFFu + ((u >> 16) & 1u);          // RNE
  return (unsigned short)(u >> 16);
}
DEV unsigned pack2(float lo, float hi){     // 2 f32 -> packed bf16x2
  return (unsigned)f2bf(lo) | ((unsigned)f2bf(hi) << 16);
}
DEV float bfLO(unsigned u){ return __builtin_bit_cast(float, u << 16); }
DEV float bfHI(unsigned u){ return __builtin_bit_cast(float, u & 0xffff0000u); }
DEV float ftanh(float x){
  float a = fabsf(x);
  float e = __expf(-2.f * a);
  float r = __builtin_amdgcn_rcpf(1.f + e);
  float t = (1.f - e) * r;
  return copysignf(t, x);
}
DEV float fsoftplus(float x){
  float e = __expf(fminf(x, 20.f));
  float s = __logf(1.f + e);
  return (x > 20.f) ? x : s;
}
// LDS-visibility barrier: lgkm drain + s_barrier, no vmcnt, no sched fences.
DEV void barrier_l(){
  asm volatile("s_waitcnt lgkmcnt(0)\n\ts_barrier" ::: "memory");
}

// Fragment conventions (verified rounds 1-6, mfma_f32_16x16x32_bf16), swapped:
//   D = A*B, A = weight tile (16 out-cols x K), B = state^T (K x 16 batch).
//   A-frag: lane l elem e: W[outcol = l&15][k = (l>>4)*8 + e]
//   B-frag: lane l elem e: h[batch = l&15][k = (l>>4)*8 + e]
//   C/D:    lane l reg r:  value(batch = l&15, outcol = tile + 4*(l>>4) + r)

// ---------------------------------------------------------------------------
// Phase A: xp = X @ Wih^T + bih + bhh (both dirs), bf16 lane-packed:
// xpF[d][s][bq][q][l][16]   (unchanged from round 6)
// ---------------------------------------------------------------------------
__global__ __launch_bounds__(256, 2) void phaseA(
    const float* __restrict__ X,
    const float* __restrict__ WihF, const float* __restrict__ bihF, const float* __restrict__ bhhF,
    const float* __restrict__ WihB, const float* __restrict__ bihB, const float* __restrict__ bhhB,
    unsigned short* __restrict__ xpF)
{
  const int bid = blockIdx.x;
  const int d = bid >> 9, s = bid & 511;
  const int ts = d ? (TT - 1 - s) : s;
  const float* W  = d ? WihB : WihF;
  const float* bi = d ? bihB : bihF;
  const float* bh = d ? bhhB : bhhF;

  const int tid = threadIdx.x, q = tid >> 6, l = tid & 63;
  const int l15 = l & 15, l4 = l >> 4;

  short8 wf[4][4];
  f32x4 bias[4];
  #pragma unroll
  for (int ni = 0; ni < 4; ++ni){
    int n = 64*q + 16*ni + l15;
    #pragma unroll
    for (int ks = 0; ks < 4; ++ks){
      const float* p = W + (size_t)n * DXX + ks*32 + l4*8;
      short8 v;
      #pragma unroll
      for (int i = 0; i < 8; ++i) v[i] = (short)f2bf(p[i]);
      wf[ni][ks] = v;
    }
    int n0 = 64*q + 16*ni + 4*l4;
    float4 b1 = *(const float4*)(bi + n0);
    float4 b2 = *(const float4*)(bh + n0);
    bias[ni][0]=b1.x+b2.x; bias[ni][1]=b1.y+b2.y; bias[ni][2]=b1.z+b2.z; bias[ni][3]=b1.w+b2.w;
  }

  #pragma unroll
  for (int bq = 0; bq < 4; ++bq){
    const float* xr = X + ((size_t)ts * 64 + 16*bq + l15) * DXX;
    short8 xf[4];
    #pragma unroll
    for (int ks = 0; ks < 4; ++ks){
      const float* p = xr + ks*32 + l4*8;
      short8 v;
      #pragma unroll
      for (int i = 0; i < 8; ++i) v[i] = (short)f2bf(p[i]);
      xf[ks] = v;
    }
    f32x4 acc[4];
    #pragma unroll
    for (int ni = 0; ni < 4; ++ni) acc[ni] = MFMA(wf[ni][0], xf[0], bias[ni]);
    #pragma unroll
    for (int ks = 1; ks < 4; ++ks)
      #pragma unroll
      for (int ni = 0; ni < 4; ++ni)
        acc[ni] = MFMA(wf[ni][ks], xf[ks], acc[ni]);

    unsigned wd[8];
    #pragma unroll
    for (int ni = 0; ni < 4; ++ni){
      wd[ni*2]   = pack2(acc[ni][0], acc[ni][1]);
      wd[ni*2+1] = pack2(acc[ni][2], acc[ni][3]);
    }
    unsigned short* dst = xpF + ((((size_t)d*TT + s)*4 + bq)*4 + q)*1024 + (size_t)l*16;
    uint4 o0 = {wd[0], wd[1], wd[2], wd[3]};
    uint4 o1 = {wd[4], wd[5], wd[6], wd[7]};
    ((uint4*)dst)[0] = o0;
    ((uint4*)dst)[1] = o1;
  }
}

// ---------------------------------------------------------------------------
// Phase B: two RNN scans, 8 blocks (dir,bq) x 512 thr: 4 compute + 4 IO waves.
// Compute: only LOADS in its vmem FIFO (xp prefetch-2); h results go to LDS
// staging. IO waves do all global stores of h.
// ---------------------------------------------------------------------------
__global__ __launch_bounds__(512, 1) void phaseB(
    const float* __restrict__ WhhF, const float* __restrict__ WhhB,
    const unsigned short* __restrict__ xpF, unsigned short* __restrict__ hF)
{
  const int dir = blockIdx.x >> 2, bq = blockIdx.x & 3;
  const float* Whh = dir ? WhhB : WhhF;
  const int tid = threadIdx.x, w = tid >> 6, l = tid & 63;
  const bool comp = (w < 4);
  const int q = w & 3;                 // compute-wave id OR io-wave id (1:1)
  const int l15 = l & 15, l4 = l >> 4;
  const int swz = (l15 & 7) << 3;
  const int rbase = l15 * 256;

  __shared__ __attribute__((aligned(16))) unsigned short hbuf[2][4096];
  __shared__ __attribute__((aligned(16))) unsigned short hres[2][4096];  // ring-2 result staging

  short8 wf[4][8];
  if (comp){
    #pragma unroll
    for (int ni = 0; ni < 4; ++ni){
      int n = 64*q + 16*ni + l15;
      #pragma unroll
      for (int ks = 0; ks < 8; ++ks){
        const float* p = Whh + (size_t)n * HH + ks*32 + l4*8;
        short8 v;
        #pragma unroll
        for (int i = 0; i < 8; ++i) v[i] = (short)f2bf(p[i]);
        wf[ni][ks] = v;
      }
    }
  }
  for (int i = tid; i < 2048; i += 512) ((unsigned*)hbuf[0])[i] = 0u;  // h_0 = 0

  const size_t strideS = 16384;   // ushorts per timestep
  const size_t laneOff = (size_t)bq*4096 + (size_t)q*1024 + (size_t)l*16;
  const unsigned short* xpP = xpF + (size_t)dir*TT*strideS + laneOff;
  unsigned short* hD = hF + (size_t)dir*TT*strideS + laneOff;

  uint4 xqA0, xqA1, xqB0, xqB1;
  if (comp){
    const uint4* p0 = (const uint4*)xpP;             xqA0 = p0[0]; xqA1 = p0[1];
    const uint4* p1 = (const uint4*)(xpP + strideS); xqB0 = p1[0]; xqB1 = p1[1];
  }
  __syncthreads();

  auto bstep = [&](int s, uint4& XQ0, uint4& XQ1){
    if (comp){
      const unsigned short* RD = hbuf[s & 1];
      unsigned short* WR = hbuf[(s & 1) ^ 1];
      // 1) LDS reads of h_{s-1}
      short8 b[8];
      #pragma unroll
      for (int ks = 0; ks < 8; ++ks)
        b[ks] = *(const short8*)(RD + ((rbase + ks*32 + l4*8) ^ swz));
      // 2) acc <- xp
      f32x4 accE[4], accO[4];
      {
        unsigned W8[8] = {XQ0.x, XQ0.y, XQ0.z, XQ0.w, XQ1.x, XQ1.y, XQ1.z, XQ1.w};
        #pragma unroll
        for (int ni = 0; ni < 4; ++ni){
          accE[ni][0] = bfLO(W8[ni*2]);   accE[ni][1] = bfHI(W8[ni*2]);
          accE[ni][2] = bfLO(W8[ni*2+1]); accE[ni][3] = bfHI(W8[ni*2+1]);
          accO[ni][0] = 0.f; accO[ni][1] = 0.f; accO[ni][2] = 0.f; accO[ni][3] = 0.f;
        }
      }
      // 3) prefetch xp for s+2 (load-only FIFO -> counted wait)
      {
        int sn = (s + 2 < TT) ? s + 2 : TT - 1;
        const uint4* src = (const uint4*)(xpP + (size_t)sn * strideS);
        XQ0 = src[0]; XQ1 = src[1];
      }
      // 4) Whh * h^T : 8 chains of depth 4
      #pragma unroll
      for (int ks = 0; ks < 8; ks += 2){
        #pragma unroll
        for (int ni = 0; ni < 4; ++ni){
          accE[ni] = MFMA(wf[ni][ks],   b[ks],   accE[ni]);
          accO[ni] = MFMA(wf[ni][ks+1], b[ks+1], accO[ni]);
        }
      }
      // 5) tanh + pack -> recurrent LDS + result staging (NO global stores)
      unsigned wd[8];
      #pragma unroll
      for (int ni = 0; ni < 4; ++ni){
        float t0 = ftanh(accE[ni][0] + accO[ni][0]);
        float t1 = ftanh(accE[ni][1] + accO[ni][1]);
        float t2 = ftanh(accE[ni][2] + accO[ni][2]);
        float t3 = ftanh(accE[ni][3] + accO[ni][3]);
        unsigned lo = pack2(t0, t1), hi = pack2(t2, t3);
        wd[ni*2] = lo; wd[ni*2+1] = hi;
        int ea = rbase + ((64*q + 16*ni + 4*l4) ^ swz);
        uint2 v; v.x = lo; v.y = hi;
        *(uint2*)(WR + ea) = v;
      }
      {
        unsigned short* st = hres[s & 1] + q*1024 + l*16;
        uint4 o0 = {wd[0], wd[1], wd[2], wd[3]};
        uint4 o1 = {wd[4], wd[5], wd[6], wd[7]};
        ((uint4*)st)[0] = o0;
        ((uint4*)st)[1] = o1;
      }
    } else {
      // IO: store h_{s-1} (slot (s&1)^1); s=0 stores junk to tg(0), fixed at s=1.
      int sg = (s > 0) ? s - 1 : 0;
      const unsigned short* src = hres[(s & 1) ^ 1] + q*1024 + l*16;
      uint4 p0 = ((const uint4*)src)[0];
      uint4 p1 = ((const uint4*)src)[1];
      size_t off = (size_t)(dir ? (TT - 1 - sg) : sg) * strideS;
      *(uint4*)(hD + off)     = p0;
      *(uint4*)(hD + off + 8) = p1;
    }
    barrier_l();
  };

  for (int s = 0; s < TT; s += 2){
    bstep(s,     xqA0, xqA1);
    bstep(s + 1, xqB0, xqB1);
  }
  if (!comp){   // final h_{511} lives in hres[1]
    const unsigned short* src = hres[1] + q*1024 + l*16;
    uint4 p0 = ((const uint4*)src)[0];
    uint4 p1 = ((const uint4*)src)[1];
    size_t off = (size_t)(dir ? 0 : (TT - 1)) * strideS;
    *(uint4*)(hD + off)     = p0;
    *(uint4*)(hD + off + 8) = p1;
  }
}

// ---------------------------------------------------------------------------
// Phase P (parallel over t): Mpre = bmu + (Wmu/3)·(hl+hr), Spre analog.
// Output lane-packed f32: MS[t][bq][q][l][8] = {mu f32x4 | sig f32x4}.
// 2048 blocks x 256 thr. Reuses the proven hbuf-swizzle + B-frag read path.
// ---------------------------------------------------------------------------
__global__ __launch_bounds__(256, 2) void phaseP(
    const float* __restrict__ Wmu, const float* __restrict__ bmu,
    const float* __restrict__ Wsig,const float* __restrict__ bsig,
    const unsigned short* __restrict__ hF, float* __restrict__ MS)
{
  const int bid = blockIdx.x;
  const int t = bid >> 2, bq = bid & 3;
  const int tid = threadIdx.x, q = tid >> 6, l = tid & 63;
  const int l15 = l & 15, l4 = l >> 4;
  const int swz = (l15 & 7) << 3;
  const int rbase = l15 * 256;

  __shared__ __attribute__((aligned(16))) unsigned short hbuf[4096];

  short8 wm[8], wsg[8];
  {
    int r = 16*q + l15;
    #pragma unroll
    for (int ks = 0; ks < 8; ++ks){
      const float* pm = Wmu  + (size_t)r * HH + ks*32 + l4*8;
      const float* ps = Wsig + (size_t)r * HH + ks*32 + l4*8;
      short8 vm, vs;
      #pragma unroll
      for (int i = 0; i < 8; ++i){
        vm[i] = (short)f2bf(pm[i] * (1.f/3.f));
        vs[i] = (short)f2bf(ps[i] * (1.f/3.f));
      }
      wm[ks] = vm; wsg[ks] = vs;
    }
  }
  f32x4 bm4, bs4;
  {
    float4 a = *(const float4*)(bmu  + 16*q + 4*l4);
    float4 b = *(const float4*)(bsig + 16*q + 4*l4);
    bm4[0]=a.x; bm4[1]=a.y; bm4[2]=a.z; bm4[3]=a.w;
    bs4[0]=b.x; bs4[1]=b.y; bs4[2]=b.z; bs4[3]=b.w;
  }

  const size_t strideS = 16384;
  const size_t laneOff = (size_t)bq*4096 + (size_t)q*1024 + (size_t)l*16;
  const unsigned short* hl = hF + (size_t)t*strideS + laneOff;
  const unsigned short* hr = hl + (size_t)TT*strideS;
  {
    uint4 a0 = ((const uint4*)hl)[0], a1 = ((const uint4*)hl)[1];
    uint4 b0 = ((const uint4*)hr)[0], b1 = ((const uint4*)hr)[1];
    unsigned HL[8] = {a0.x,a0.y,a0.z,a0.w,a1.x,a1.y,a1.z,a1.w};
    unsigned HR[8] = {b0.x,b0.y,b0.z,b0.w,b1.x,b1.y,b1.z,b1.w};
    #pragma unroll
    for (int ni = 0; ni < 4; ++ni){
      float h0 = bfLO(HL[ni*2])   + bfLO(HR[ni*2]);
      float h1 = bfHI(HL[ni*2])   + bfHI(HR[ni*2]);
      float h2 = bfLO(HL[ni*2+1]) + bfLO(HR[ni*2+1]);
      float h3 = bfHI(HL[ni*2+1]) + bfHI(HR[ni*2+1]);
      int ea = rbase + ((64*q + 16*ni + 4*l4) ^ swz);
      uint2 v; v.x = pack2(h0, h1); v.y = pack2(h2, h3);
      *(uint2*)(hbuf + ea) = v;
    }
  }
  __syncthreads();

  short8 hb[8];
  #pragma unroll
  for (int ks = 0; ks < 8; ++ks)
    hb[ks] = *(const short8*)(hbuf + ((rbase + ks*32 + l4*8) ^ swz));
  const f32x4 zero4 = {0.f,0.f,0.f,0.f};
  f32x4 am0 = MFMA(wm[0],  hb[0], bm4);
  f32x4 as0 = MFMA(wsg[0], hb[0], bs4);
  f32x4 am1 = MFMA(wm[4],  hb[4], zero4);
  f32x4 as1 = MFMA(wsg[4], hb[4], zero4);
  #pragma unroll
  for (int ks = 1; ks < 4; ++ks){
    am0 = MFMA(wm[ks],    hb[ks],   am0);
    as0 = MFMA(wsg[ks],   hb[ks],   as0);
    am1 = MFMA(wm[ks+4],  hb[ks+4], am1);
    as1 = MFMA(wsg[ks+4], hb[ks+4], as1);
  }
  f32x4 mu = am0 + am1;
  f32x4 sg = as0 + as1;
  float* dst = MS + ((((size_t)t*4 + bq)*4 + q)*64 + (size_t)l)*8;
  *(float4*)dst       = *(float4*)&mu;
  *(float4*)(dst + 4) = *(float4*)&sg;
}

// ---------------------------------------------------------------------------
// Phase C: latent scan, 4 blocks x 512 thr: 4 compute + 4 IO waves.
// Compute: loads only (Mpre/Spre/eps prefetch-2), LDS-only recurrence,
// results -> LDS res staging. IO waves do all out stores.
// ---------------------------------------------------------------------------
__global__ __launch_bounds__(512, 1) void phaseC(
    const float* __restrict__ Wt,  const float* __restrict__ bt,
    const float* __restrict__ Wmu, const float* __restrict__ Wsig,
    const float* __restrict__ eps, const float* __restrict__ MS,
    float* __restrict__ out)
{
  const int bq = blockIdx.x;
  const int tid = threadIdx.x, w = tid >> 6, l = tid & 63;
  const bool comp = (w < 4);
  const int q = w & 3;
  const int l15 = l & 15, l4 = l >> 4;
  const int swz = (l15 & 7) << 3;
  const int rbase = l15 * 256;
  const int zrbase = l15 * 64;

  __shared__ __attribute__((aligned(16))) unsigned short zbuf[1024];   // 16 x 64 bf16
  __shared__ __attribute__((aligned(16))) unsigned short ubuf[4096];   // 16 x 256 bf16 (tanh)
  __shared__ __attribute__((aligned(16))) float res[3072];             // [4][64][12] f32

  short8 wtf[4][2]; f32x4 btb[4];
  short8 wm[8], wsg[8];
  if (comp){
    #pragma unroll
    for (int ni = 0; ni < 4; ++ni){
      int n = 64*q + 16*ni + l15;
      #pragma unroll
      for (int ks = 0; ks < 2; ++ks){
        const float* p = Wt + (size_t)n * DZZ + ks*32 + l4*8;
        short8 v;
        #pragma unroll
        for (int i = 0; i < 8; ++i) v[i] = (short)f2bf(p[i]);
        wtf[ni][ks] = v;
      }
      float4 b4 = *(const float4*)(bt + 64*q + 16*ni + 4*l4);
      btb[ni][0]=b4.x; btb[ni][1]=b4.y; btb[ni][2]=b4.z; btb[ni][3]=b4.w;
    }
    int r = 16*q + l15;
    #pragma unroll
    for (int ks = 0; ks < 8; ++ks){
      const float* pm = Wmu  + (size_t)r * HH + ks*32 + l4*8;
      const float* ps = Wsig + (size_t)r * HH + ks*32 + l4*8;
      short8 vm, vs;
      #pragma unroll
      for (int i = 0; i < 8; ++i){
        vm[i] = (short)f2bf(pm[i] * (1.f/3.f));
        vs[i] = (short)f2bf(ps[i] * (1.f/3.f));
      }
      wm[ks] = vm; wsg[ks] = vs;
    }
  }
  if (tid < 512) ((unsigned*)zbuf)[tid] = 0u;   // z_0 = 0 (512 words)

  const float* msP = MS + (((size_t)bq*4 + q)*64 + (size_t)l)*8;        // + t*8192
  const float* eP  = eps + ((size_t)(16*bq + l15))*64 + 16*q + 4*l4;    // + t*4096
  const int resoff = (q*64 + l)*12;
  const size_t TBZ = (size_t)TT * 64 * 64;
  const f32x4 zero4 = {0.f,0.f,0.f,0.f};

  f32x4 MPa, SPa, EFa, MPb, SPb, EFb;
  if (comp){
    float4 m0 = *(const float4*)(msP);         float4 s0 = *(const float4*)(msP + 4);
    float4 m1 = *(const float4*)(msP + 8192);  float4 s1 = *(const float4*)(msP + 8192 + 4);
    float4 e0 = *(const float4*)(eP);
    float4 e1 = *(const float4*)(eP + 4096);
    MPa[0]=m0.x;MPa[1]=m0.y;MPa[2]=m0.z;MPa[3]=m0.w;
    SPa[0]=s0.x;SPa[1]=s0.y;SPa[2]=s0.z;SPa[3]=s0.w;
    MPb[0]=m1.x;MPb[1]=m1.y;MPb[2]=m1.z;MPb[3]=m1.w;
    SPb[0]=s1.x;SPb[1]=s1.y;SPb[2]=s1.z;SPb[3]=s1.w;
    EFa[0]=e0.x;EFa[1]=e0.y;EFa[2]=e0.z;EFa[3]=e0.w;
    EFb[0]=e1.x;EFb[1]=e1.y;EFb[2]=e1.z;EFb[3]=e1.w;
  }
  __syncthreads();

  auto cstep = [&](int t, f32x4& MP, f32x4& SP, f32x4& EF){
    if (comp){
      // sect1: transition + tanh -> ubuf
      short8 zb0 = *(const short8*)(zbuf + ((zrbase +  0 + l4*8) ^ swz));
      short8 zb1 = *(const short8*)(zbuf + ((zrbase + 32 + l4*8) ^ swz));
      f32x4 at[4];
      #pragma unroll
      for (int ni = 0; ni < 4; ++ni) at[ni] = MFMA(wtf[ni][0], zb0, btb[ni]);
      #pragma unroll
      for (int ni = 0; ni < 4; ++ni) at[ni] = MFMA(wtf[ni][1], zb1, at[ni]);
      #pragma unroll
      for (int ni = 0; ni < 4; ++ni){
        float u0 = ftanh(at[ni][0]), u1 = ftanh(at[ni][1]);
        float u2 = ftanh(at[ni][2]), u3 = ftanh(at[ni][3]);
        int ea = rbase + ((64*q + 16*ni + 4*l4) ^ swz);
        uint2 v; v.x = pack2(u0, u1); v.y = pack2(u2, u3);
        *(uint2*)(ubuf + ea) = v;
      }
    } else {
      // IO: store results of t-1 (t=0 stores junk to ob(0), fixed at t=1)
      int tp = (t > 0) ? t - 1 : 0;
      const float* rs = res + resoff;
      float4 vz = *(const float4*)(rs);
      float4 vm = *(const float4*)(rs + 4);
      float4 vs = *(const float4*)(rs + 8);
      size_t ob = ((size_t)tp*64 + 16*bq + l15)*64 + 16*q + 4*l4;
      *(float4*)(out + ob)         = vz;
      *(float4*)(out + TBZ + ob)   = vm;
      *(float4*)(out + 2*TBZ + ob) = vs;
    }
    barrier_l();   // B1: ubuf visible

    if (comp){
      // sect2: mu/sig = Mpre/Spre + (Wmu/3)·u, reparam, z -> zbuf, res -> LDS
      short8 hb[8];
      #pragma unroll
      for (int ks = 0; ks < 8; ++ks)
        hb[ks] = *(const short8*)(ubuf + ((rbase + ks*32 + l4*8) ^ swz));
      f32x4 am0 = MFMA(wm[0],  hb[0], MP);
      f32x4 as0 = MFMA(wsg[0], hb[0], SP);
      f32x4 am1 = MFMA(wm[4],  hb[4], zero4);
      f32x4 as1 = MFMA(wsg[4], hb[4], zero4);
      #pragma unroll
      for (int ks = 1; ks < 4; ++ks){
        am0 = MFMA(wm[ks],    hb[ks],   am0);
        as0 = MFMA(wsg[ks],   hb[ks],   as0);
        am1 = MFMA(wm[ks+4],  hb[ks+4], am1);
        as1 = MFMA(wsg[ks+4], hb[ks+4], as1);
      }
      f32x4 mu = am0 + am1;
      f32x4 sg = as0 + as1;
      f32x4 dz, dsp;
      #pragma unroll
      for (int reg = 0; reg < 4; ++reg){
        float sp = fsoftplus(sg[reg]);
        dz[reg] = __builtin_fmaf(sp, EF[reg], mu[reg]);
        dsp[reg] = sp;
      }
      {
        int zea = zrbase + ((16*q + 4*l4) ^ swz);
        uint2 v; v.x = pack2(dz[0], dz[1]); v.y = pack2(dz[2], dz[3]);
        *(uint2*)(zbuf + zea) = v;
      }
      {
        float* rw = res + resoff;
        *(float4*)(rw)     = *(float4*)&dz;
        *(float4*)(rw + 4) = *(float4*)&mu;
        *(float4*)(rw + 8) = *(float4*)&dsp;
      }
      // prefetch t+2 (pure-load FIFO)
      {
        int tn = (t + 2 < TT) ? t + 2 : TT - 1;
        float4 m = *(const float4*)(msP + (size_t)tn*8192);
        float4 s = *(const float4*)(msP + (size_t)tn*8192 + 4);
        float4 e = *(const float4*)(eP + (size_t)tn*4096);
        MP[0]=m.x;MP[1]=m.y;MP[2]=m.z;MP[3]=m.w;
        SP[0]=s.x;SP[1]=s.y;SP[2]=s.z;SP[3]=s.w;
        EF[0]=e.x;EF[1]=e.y;EF[2]=e.z;EF[3]=e.w;
      }
    }
    barrier_l();   // B2: zbuf + res visible
  };

  for (int t = 0; t < TT; t += 2){
    cstep(t,     MPa, SPa, EFa);
    cstep(t + 1, MPb, SPb, EFb);
  }
  if (!comp){   // final t = 511 results
    const float* rs = res + resoff;
    float4 vz = *(const float4*)(rs);
    float4 vm = *(const float4*)(rs + 4);
    float4 vs = *(const float4*)(rs + 8);
    size_t ob = ((size_t)(TT-1)*64 + 16*bq + l15)*64 + 16*q + 4*l4;
    *(float4*)(out + ob)         = vz;
    *(float4*)(out + TBZ + ob)   = vm;
    *(float4*)(out + 2*TBZ + ob) = vs;
  }
}

// ---------------------------------------------------------------------------
extern "C" void kernel_launch(void* const* d_in, const int* in_sizes, int n_in,
                              void* d_out, int out_size, void* d_ws, size_t ws_size,
                              hipStream_t stream)
{
  const float* X      = (const float*)d_in[0];
  const float* Wih_f  = (const float*)d_in[1];
  const float* Whh_f  = (const float*)d_in[2];
  const float* bih_f  = (const float*)d_in[3];
  const float* bhh_f  = (const float*)d_in[4];
  const float* Wih_b  = (const float*)d_in[5];
  const float* Whh_b  = (const float*)d_in[6];
  const float* bih_b  = (const float*)d_in[7];
  const float* bhh_b  = (const float*)d_in[8];
  const float* Wt     = (const float*)d_in[9];
  const float* bt     = (const float*)d_in[10];
  const float* Wmu    = (const float*)d_in[11];
  const float* bmu    = (const float*)d_in[12];
  const float* Wsig   = (const float*)d_in[13];
  const float* bsig   = (const float*)d_in[14];
  const float* eps    = (const float*)d_in[15];

  // Workspace: xpF (33.5MB) + hF (33.5MB); MS (16.8MB) aliases xpF
  // (phaseP runs after phaseB, which is the last reader of xpF).
  unsigned short* xpF = (unsigned short*)d_ws;
  unsigned short* hF  = xpF + (size_t)2 * TT * 16384;
  float* MS = (float*)d_ws;

  phaseA<<<dim3(1024), dim3(256), 0, stream>>>(X, Wih_f, bih_f, bhh_f, Wih_b, bih_b, bhh_b, xpF);
  phaseB<<<dim3(8), dim3(512), 0, stream>>>(Whh_f, Whh_b, xpF, hF);
  phaseP<<<dim3(2048), dim3(256), 0, stream>>>(Wmu, bmu, Wsig, bsig, hF, MS);
  phaseC<<<dim3(4), dim3(512), 0, stream>>>(Wt, bt, Wmu, Wsig, eps, MS, (float*)d_out);
}